// Round 7
// baseline (108.799 us; speedup 1.0000x reference)
//
#include <hip/hip_runtime.h>
#include <hip/hip_bf16.h>

typedef _Float16 f16x8 __attribute__((ext_vector_type(8)));
typedef _Float16 f16x4 __attribute__((ext_vector_type(4)));
typedef float    f32x4 __attribute__((ext_vector_type(4)));

constexpr int BB = 4;
constexpr int CH = 128;
constexpr int PC = 64;
constexpr int NN = 4096;

// ---------------------------------------------------------------------------
// proj: one launch, grid (N/16, 2*B). role = y>>2 (0: pos-projection + sq,
// 1: value-projection). Verified r5/r6; eqF stores nontemporal.
// ---------------------------------------------------------------------------
__global__ __launch_bounds__(256) void proj_kernel(
    const float* __restrict__ pos_bot,  // [B,64,N]
    const float* __restrict__ corr,     // [B,128,N]
    const float* __restrict__ Wp,       // [64,64]
    const float* __restrict__ bp,       // [64]
    const float* __restrict__ Wv,       // [128,128]
    const float* __restrict__ bv,       // [128]
    _Float16* __restrict__ xbuf,        // [B,N,64]  (re-read by gram: cached)
    float*    __restrict__ sq,          // [B,N]     (re-read by gram: cached)
    float*    __restrict__ eqF)         // [B,N,128] (write-once: nt)
{
    const int tid  = threadIdx.x;
    const int wid  = tid >> 6;
    const int lane = tid & 63;
    const int l15  = lane & 15;
    const int lg   = lane >> 4;
    const int b    = blockIdx.y & 3;
    const int n    = blockIdx.x * 16 + l15;

    if ((blockIdx.y >> 2) == 0) {
        // ---- pos projection: x~ = f16(Wp @ pos_bot + bp), sq = ||x~||^2 ----
        const int mt = wid;
        f16x8 wf[2], pb[2];
#pragma unroll
        for (int ks = 0; ks < 2; ++ks) {
            const float* wp = Wp + (mt * 16 + l15) * PC + ks * 32 + lg * 8;
            f32x4 w0 = *reinterpret_cast<const f32x4*>(wp);
            f32x4 w1 = *reinterpret_cast<const f32x4*>(wp + 4);
            f16x8 f;
#pragma unroll
            for (int e = 0; e < 4; ++e) { f[e] = (_Float16)w0[e]; f[e + 4] = (_Float16)w1[e]; }
            wf[ks] = f;
            f16x8 g;
#pragma unroll
            for (int e = 0; e < 8; ++e) {
                const int c = ks * 32 + lg * 8 + e;
                g[e] = (_Float16)pos_bot[((size_t)(b * PC + c)) * NN + n];
            }
            pb[ks] = g;
        }

        f32x4 acc = {0.f, 0.f, 0.f, 0.f};
        acc = __builtin_amdgcn_mfma_f32_16x16x32_f16(wf[0], pb[0], acc, 0, 0, 0);
        acc = __builtin_amdgcn_mfma_f32_16x16x32_f16(wf[1], pb[1], acc, 0, 0, 0);

        float partial = 0.f;
        f16x4 h4;
#pragma unroll
        for (int r = 0; r < 4; ++r) {
            const int o = mt * 16 + lg * 4 + r;
            const float v = acc[r] + bp[o];
            const _Float16 h = (_Float16)v;
            h4[r] = h;
            const float hf = (float)h;
            partial = fmaf(hf, hf, partial);
        }
        *reinterpret_cast<f16x4*>(xbuf + ((size_t)(b * NN + n)) * PC + mt * 16 + lg * 4) = h4;

        partial += __shfl_xor(partial, 16);
        partial += __shfl_xor(partial, 32);
        __shared__ float psum[4][16];
        if (lane < 16) psum[wid][l15] = partial;
        __syncthreads();
        if (tid < 16)
            sq[b * NN + blockIdx.x * 16 + tid] =
                psum[0][tid] + psum[1][tid] + psum[2][tid] + psum[3][tid];
        return;
    }

    // ---- value projection: eqF = Wv @ corr + bv ----
    f16x8 cb[4];
#pragma unroll
    for (int ks = 0; ks < 4; ++ks) {
        f16x8 g;
#pragma unroll
        for (int e = 0; e < 8; ++e) {
            const int c = ks * 32 + lg * 8 + e;
            g[e] = (_Float16)corr[((size_t)(b * CH + c)) * NN + n];
        }
        cb[ks] = g;
    }
#pragma unroll
    for (int half = 0; half < 2; ++half) {
        const int ot = wid + half * 4;   // 0..7
        f32x4 acc = {0.f, 0.f, 0.f, 0.f};
#pragma unroll
        for (int ks = 0; ks < 4; ++ks) {
            const float* wv = Wv + (ot * 16 + l15) * CH + ks * 32 + lg * 8;
            f32x4 w0 = *reinterpret_cast<const f32x4*>(wv);
            f32x4 w1 = *reinterpret_cast<const f32x4*>(wv + 4);
            f16x8 f;
#pragma unroll
            for (int e = 0; e < 4; ++e) { f[e] = (_Float16)w0[e]; f[e + 4] = (_Float16)w1[e]; }
            acc = __builtin_amdgcn_mfma_f32_16x16x32_f16(f, cb[ks], acc, 0, 0, 0);
        }
        f32x4 o4;
#pragma unroll
        for (int r = 0; r < 4; ++r) o4[r] = acc[r] + bv[ot * 16 + lg * 4 + r];
        __builtin_nontemporal_store(
            o4, reinterpret_cast<f32x4*>(eqF + ((size_t)(b * NN + n)) * CH + ot * 16 + lg * 4));
    }
}

// ---------------------------------------------------------------------------
// gram: read-locality version.
// Flat grid 2048 blocks, XCD-band swizzle: xcd = bid&7 owns i-rows
// [xcd*512, xcd*512+512) for ALL j and batches -> per-XCD L2 working set =
// A-band 64 KB + full B 512 KB per batch, first-touch HBM only (~20 MB total
// reads vs ~140 MB in r1-r6; this was the invariant cost across all prior
// variants). Block tile 256i x 128j, 4 waves 2x2 (wave 128x64). No LDS, no
// barriers. Transient acc; af reloaded per it from L1. NT scatter stores
// (r1-verified D-layout: swapped mfma(bf,af): i=l15, j=lg*4+r).
// ---------------------------------------------------------------------------
__global__ __launch_bounds__(256) void gram_kernel(
    const _Float16* __restrict__ xbuf,  // [B,N,64]
    const float*    __restrict__ sq,    // [B,N]
    const float*    __restrict__ beta,  // [1]
    float*          __restrict__ out)   // [B,N,N]
{
    const int tid  = threadIdx.x;
    const int wid  = tid >> 6;
    const int lane = tid & 63;
    const int l15  = lane & 15;
    const int lg   = lane >> 4;

    // swizzle: bid -> (xcd i-band, j tile, batch)
    const int bid  = blockIdx.x;
    const int xcd  = bid & 7;
    const int k    = bid >> 3;          // 0..255
    const int jt32 = k & 31;            // j tile (128 wide)
    const int i2   = (k >> 5) & 1;      // which 256-row half of the band
    const int b    = k >> 6;            // batch
    const int ib   = xcd * 512 + i2 * 256;
    const int jb   = jt32 * 128;

    const int wib  = ib + (wid >> 1) * 128;   // wave i base (128 rows)
    const int wjb  = jb + (wid & 1) * 64;     // wave j base (64 cols)

    const _Float16* xb  = xbuf + (size_t)b * NN * PC;
    const float*    sqb = sq + (size_t)b * NN;

    const float bs   = -beta[0] * 1.44269504088896f;  // exp(-b*d2)=exp2(bs*d2)
    const float m2bs = -2.f * bs;

    // B fragments + tj for this wave's 64 j (held across all it).
    f16x8 bf[4][2];
    f32x4 tj[4];
#pragma unroll
    for (int jt = 0; jt < 4; ++jt) {
#pragma unroll
        for (int ks = 0; ks < 2; ++ks)
            bf[jt][ks] = *reinterpret_cast<const f16x8*>(
                xb + (size_t)(wjb + jt * 16 + l15) * PC + ks * 32 + lg * 8);
        f32x4 s = *reinterpret_cast<const f32x4*>(sqb + wjb + jt * 16 + lg * 4);
        tj[jt] = s * bs;
    }

    for (int it = 0; it < 8; ++it) {
        const int i = wib + it * 16 + l15;
        const f16x8 af0 = *reinterpret_cast<const f16x8*>(xb + (size_t)i * PC + lg * 8);
        const f16x8 af1 = *reinterpret_cast<const f16x8*>(xb + (size_t)i * PC + 32 + lg * 8);
        const float ti  = bs * sqb[i];
        float* orow = out + ((size_t)(b * NN + i)) * NN + wjb;

#pragma unroll
        for (int jt = 0; jt < 4; ++jt) {
            f32x4 z = {0.f, 0.f, 0.f, 0.f};
            f32x4 acc = __builtin_amdgcn_mfma_f32_16x16x32_f16(bf[jt][0], af0, z, 0, 0, 0);
            acc = __builtin_amdgcn_mfma_f32_16x16x32_f16(bf[jt][1], af1, acc, 0, 0, 0);
            f32x4 v;
#pragma unroll
            for (int r = 0; r < 4; ++r)
                v[r] = __builtin_amdgcn_exp2f(fmaf(m2bs, acc[r], ti + tj[jt][r]));
            __builtin_nontemporal_store(
                v, reinterpret_cast<f32x4*>(orow + jt * 16 + lg * 4));
        }
    }
}

extern "C" void kernel_launch(void* const* d_in, const int* in_sizes, int n_in,
                              void* d_out, int out_size, void* d_ws, size_t ws_size,
                              hipStream_t stream) {
    const float* pos_bot = (const float*)d_in[0];
    const float* corr    = (const float*)d_in[1];
    const float* Wp      = (const float*)d_in[2];
    const float* bp      = (const float*)d_in[3];
    const float* Wv      = (const float*)d_in[4];
    const float* bv      = (const float*)d_in[5];
    const float* beta    = (const float*)d_in[6];

    float* out = (float*)d_out;                       // kernel [B,N,N]
    float* eqF = out + (size_t)BB * NN * NN;          // equation_F [B,N,128]

    _Float16* xbuf = (_Float16*)d_ws;                 // 2 MB
    float* sq = (float*)((char*)d_ws + (size_t)BB * NN * PC * sizeof(_Float16));

    proj_kernel<<<dim3(NN / 16, 2 * BB), 256, 0, stream>>>(
        pos_bot, corr, Wp, bp, Wv, bv, xbuf, sq, eqF);

    gram_kernel<<<dim3(2048), 256, 0, stream>>>(xbuf, sq, beta, out);
}

// Round 8
// 70.379 us; speedup vs baseline: 1.5459x; 1.5459x over previous
//
#include <hip/hip_runtime.h>
#include <hip/hip_bf16.h>

typedef _Float16 f16x8 __attribute__((ext_vector_type(8)));
typedef _Float16 f16x4 __attribute__((ext_vector_type(4)));
typedef float    f32x4 __attribute__((ext_vector_type(4)));

constexpr int BB = 4;
constexpr int CH = 128;
constexpr int PC = 64;
constexpr int NN = 4096;

// ---------------------------------------------------------------------------
// proj: one launch, grid (N/16, 2*B). role = y>>2 (0: pos-projection + sq,
// 1: value-projection). Unchanged from r6 (part of the 70.6 baseline).
// ---------------------------------------------------------------------------
__global__ __launch_bounds__(256) void proj_kernel(
    const float* __restrict__ pos_bot,  // [B,64,N]
    const float* __restrict__ corr,     // [B,128,N]
    const float* __restrict__ Wp,       // [64,64]
    const float* __restrict__ bp,       // [64]
    const float* __restrict__ Wv,       // [128,128]
    const float* __restrict__ bv,       // [128]
    _Float16* __restrict__ xbuf,        // [B,N,64]  (re-read by gram: cached)
    float*    __restrict__ sq,          // [B,N]     (re-read by gram: cached)
    float*    __restrict__ eqF)         // [B,N,128] (write-once: nt)
{
    const int tid  = threadIdx.x;
    const int wid  = tid >> 6;
    const int lane = tid & 63;
    const int l15  = lane & 15;
    const int lg   = lane >> 4;
    const int b    = blockIdx.y & 3;
    const int n    = blockIdx.x * 16 + l15;

    if ((blockIdx.y >> 2) == 0) {
        // ---- pos projection: x~ = f16(Wp @ pos_bot + bp), sq = ||x~||^2 ----
        const int mt = wid;
        f16x8 wf[2], pb[2];
#pragma unroll
        for (int ks = 0; ks < 2; ++ks) {
            const float* wp = Wp + (mt * 16 + l15) * PC + ks * 32 + lg * 8;
            f32x4 w0 = *reinterpret_cast<const f32x4*>(wp);
            f32x4 w1 = *reinterpret_cast<const f32x4*>(wp + 4);
            f16x8 f;
#pragma unroll
            for (int e = 0; e < 4; ++e) { f[e] = (_Float16)w0[e]; f[e + 4] = (_Float16)w1[e]; }
            wf[ks] = f;
            f16x8 g;
#pragma unroll
            for (int e = 0; e < 8; ++e) {
                const int c = ks * 32 + lg * 8 + e;
                g[e] = (_Float16)pos_bot[((size_t)(b * PC + c)) * NN + n];
            }
            pb[ks] = g;
        }

        f32x4 acc = {0.f, 0.f, 0.f, 0.f};
        acc = __builtin_amdgcn_mfma_f32_16x16x32_f16(wf[0], pb[0], acc, 0, 0, 0);
        acc = __builtin_amdgcn_mfma_f32_16x16x32_f16(wf[1], pb[1], acc, 0, 0, 0);

        float partial = 0.f;
        f16x4 h4;
#pragma unroll
        for (int r = 0; r < 4; ++r) {
            const int o = mt * 16 + lg * 4 + r;
            const float v = acc[r] + bp[o];
            const _Float16 h = (_Float16)v;
            h4[r] = h;
            const float hf = (float)h;
            partial = fmaf(hf, hf, partial);
        }
        *reinterpret_cast<f16x4*>(xbuf + ((size_t)(b * NN + n)) * PC + mt * 16 + lg * 4) = h4;

        partial += __shfl_xor(partial, 16);
        partial += __shfl_xor(partial, 32);
        __shared__ float psum[4][16];
        if (lane < 16) psum[wid][l15] = partial;
        __syncthreads();
        if (tid < 16)
            sq[b * NN + blockIdx.x * 16 + tid] =
                psum[0][tid] + psum[1][tid] + psum[2][tid] + psum[3][tid];
        return;
    }

    // ---- value projection: eqF = Wv @ corr + bv ----
    f16x8 cb[4];
#pragma unroll
    for (int ks = 0; ks < 4; ++ks) {
        f16x8 g;
#pragma unroll
        for (int e = 0; e < 8; ++e) {
            const int c = ks * 32 + lg * 8 + e;
            g[e] = (_Float16)corr[((size_t)(b * CH + c)) * NN + n];
        }
        cb[ks] = g;
    }
#pragma unroll
    for (int half = 0; half < 2; ++half) {
        const int ot = wid + half * 4;   // 0..7
        f32x4 acc = {0.f, 0.f, 0.f, 0.f};
#pragma unroll
        for (int ks = 0; ks < 4; ++ks) {
            const float* wv = Wv + (ot * 16 + l15) * CH + ks * 32 + lg * 8;
            f32x4 w0 = *reinterpret_cast<const f32x4*>(wv);
            f32x4 w1 = *reinterpret_cast<const f32x4*>(wv + 4);
            f16x8 f;
#pragma unroll
            for (int e = 0; e < 4; ++e) { f[e] = (_Float16)w0[e]; f[e + 4] = (_Float16)w1[e]; }
            acc = __builtin_amdgcn_mfma_f32_16x16x32_f16(f, cb[ks], acc, 0, 0, 0);
        }
        f32x4 o4;
#pragma unroll
        for (int r = 0; r < 4; ++r) o4[r] = acc[r] + bv[ot * 16 + lg * 4 + r];
        __builtin_nontemporal_store(
            o4, reinterpret_cast<f32x4*>(eqF + ((size_t)(b * NN + n)) * CH + ot * 16 + lg * 4));
    }
}

// ---------------------------------------------------------------------------
// gram: r6 pipeline (MFMA -> exp2 -> LDS transpose -> contiguous NT stores)
// with ZERO barriers. Each wave stages its own 16x128 fragment in a PRIVATE
// LDS quadrant (lds[wid], pad 132 -> 2-way bank alias, free). Intra-wave
// ds_write->ds_read ordering is lgkmcnt only, so no s_waitcnt vmcnt(0) is
// ever emitted: NT stores are fire-and-forget for the whole kernel (r6's
// __syncthreads forced a DRAM-completion drain of 32 KB per slice, 8x/block
// -> the 4.2 vs 6.9 TB/s gap). Each store instr = two 512 B contiguous runs
// (full-line NT, per r7's scatter lesson).
// Block 256 thr (4 waves), tile 64i x 512j; wave w owns cols [w*128,+128).
// grid (N/512, N/64, B) = 2048 blocks.
// ---------------------------------------------------------------------------
__global__ __launch_bounds__(256) void gram_kernel(
    const _Float16* __restrict__ xbuf,  // [B,N,64]
    const float*    __restrict__ sq,    // [B,N]
    const float*    __restrict__ beta,  // [1]
    float*          __restrict__ out)   // [B,N,N]
{
    const int tid  = threadIdx.x;
    const int wid  = tid >> 6;
    const int lane = tid & 63;
    const int l15  = lane & 15;
    const int lg   = lane >> 4;
    const int b    = blockIdx.z;
    const int jb   = blockIdx.x * 512;
    const int rb   = blockIdx.y * 64;
    const int wjb  = jb + wid * 128;          // wave's 128-col range

    const _Float16* xb  = xbuf + (size_t)b * NN * PC;
    const float*    sqb = sq + (size_t)b * NN;

    const float bs   = -beta[0] * 1.44269504088896f;  // exp(-b*d2)=exp2(bs*d2)
    const float m2bs = -2.f * bs;

    // B fragments + tj for this wave's 128 j (held across all 4 slices).
    f16x8 bf[8][2];
    float tj[8];
#pragma unroll
    for (int jtf = 0; jtf < 8; ++jtf) {
        const int j = wjb + jtf * 16 + l15;
#pragma unroll
        for (int ks = 0; ks < 2; ++ks)
            bf[jtf][ks] = *reinterpret_cast<const f16x8*>(
                xb + (size_t)j * PC + ks * 32 + lg * 8);
        tj[jtf] = bs * sqb[j];
    }

    __shared__ float lds[4][16][132];   // per-wave private quadrant

    for (int sl = 0; sl < 4; ++sl) {
        const int ibase = rb + sl * 16;

        const f16x8 af0 = *reinterpret_cast<const f16x8*>(
            xb + (size_t)(ibase + l15) * PC + lg * 8);
        const f16x8 af1 = *reinterpret_cast<const f16x8*>(
            xb + (size_t)(ibase + l15) * PC + 32 + lg * 8);

        f32x4 acc[8];
#pragma unroll
        for (int jtf = 0; jtf < 8; ++jtf) {
            f32x4 z = {0.f, 0.f, 0.f, 0.f};
            acc[jtf] = __builtin_amdgcn_mfma_f32_16x16x32_f16(af0, bf[jtf][0], z, 0, 0, 0);
        }
#pragma unroll
        for (int jtf = 0; jtf < 8; ++jtf)
            acc[jtf] = __builtin_amdgcn_mfma_f32_16x16x32_f16(af1, bf[jtf][1], acc[jtf], 0, 0, 0);

        const f32x4 sv = *reinterpret_cast<const f32x4*>(sqb + ibase + lg * 4);

        // transpose into the wave's private LDS quadrant (no cross-wave sync)
#pragma unroll
        for (int jtf = 0; jtf < 8; ++jtf) {
#pragma unroll
            for (int r = 0; r < 4; ++r) {
                const float ti = bs * sv[r];
                float arg = fminf(fmaf(m2bs, acc[jtf][r], ti + tj[jtf]), 0.f);
                lds[wid][lg * 4 + r][jtf * 16 + l15] = __builtin_amdgcn_exp2f(arg);
            }
        }

        // copy-out: 16 rows x 128 cols; each instr = 2 rows x 512 B contig, nt.
#pragma unroll
        for (int k = 0; k < 8; ++k) {
            const int row = 2 * k + (lane >> 5);
            const int col = (lane & 31) * 4;
            const f32x4 v = *reinterpret_cast<const f32x4*>(&lds[wid][row][col]);
            __builtin_nontemporal_store(
                v, reinterpret_cast<f32x4*>(
                       out + ((size_t)(b * NN + ibase + row)) * NN + wjb + col));
        }
    }
}

extern "C" void kernel_launch(void* const* d_in, const int* in_sizes, int n_in,
                              void* d_out, int out_size, void* d_ws, size_t ws_size,
                              hipStream_t stream) {
    const float* pos_bot = (const float*)d_in[0];
    const float* corr    = (const float*)d_in[1];
    const float* Wp      = (const float*)d_in[2];
    const float* bp      = (const float*)d_in[3];
    const float* Wv      = (const float*)d_in[4];
    const float* bv      = (const float*)d_in[5];
    const float* beta    = (const float*)d_in[6];

    float* out = (float*)d_out;                       // kernel [B,N,N]
    float* eqF = out + (size_t)BB * NN * NN;          // equation_F [B,N,128]

    _Float16* xbuf = (_Float16*)d_ws;                 // 2 MB
    float* sq = (float*)((char*)d_ws + (size_t)BB * NN * PC * sizeof(_Float16));

    proj_kernel<<<dim3(NN / 16, 2 * BB), 256, 0, stream>>>(
        pos_bot, corr, Wp, bp, Wv, bv, xbuf, sq, eqF);

    gram_kernel<<<dim3(NN / 512, NN / 64, BB), 256, 0, stream>>>(
        xbuf, sq, beta, out);
}